// Round 9
// baseline (1879.031 us; speedup 1.0000x reference)
//
#include <hip/hip_runtime.h>
#include <hip/hip_bf16.h>
#include <math.h>

#ifndef __has_builtin
#define __has_builtin(x) 0
#endif

typedef unsigned int uint;
typedef unsigned short ushort;
typedef _Float16 half2_t __attribute__((ext_vector_type(2)));

// Problem constants: B=64, T=512, V=30000, E=256, H=256, K=9. 4H = 1024.
//
// ROOFLINE DIAGNOSIS (rounds 5-8): lstm step 4660 cyc = 94% of the per-CU
// VMEM-BW floor for its 256 KB/step stream tier (60 B/cyc/CU, m56). Three
// schedule rewrites were flat because bandwidth floors don't schedule away.
// THIS ROUND: shrink the streamed bytes. W compressed to e5m2 (= fp16's top
// byte; decode = 1 v_perm_b32 per gate-pair) in the LDS + stream tiers:
//   REG    28 k-pairs fp16 (56 uints, named scalars — decode-free)
//   LDS    76 k-pairs e5m2 (19 uint4-groups, 152 KB, 4 pairs/uint4)
//   STREAM 24 k-pairs e5m2 (6 uint4/thread = 48 KB/block/step, was 256 KB)
// New per-step budget: VMEM ~820 cyc, LDS ~1830, VALU ~2600 (+perms) ->
// VALU-bound. e5m2 encode uses round-to-nearest (add 0x80, truncate).
#define WREG_UINTS (28 * 2 * 512)          // 28672
#define WLDS_U4    (19 * 512)              // 9728 uint4 = 155648 B
#define WSTR_U4    (6 * 512)               // 3072 uint4 = 49152 B

__device__ __forceinline__ float sigm(float x) {
    return __fdividef(1.0f, 1.0f + __expf(-x));
}
__device__ __forceinline__ float tanh_fast(float x) {
    float sg = __fdividef(1.0f, 1.0f + __expf(-2.0f * x));
    return sg + sg - 1.0f;
}
__device__ __forceinline__ float dot2f(uint w, uint h, float acc) {
#if __has_builtin(__builtin_amdgcn_fdot2)
    return __builtin_amdgcn_fdot2(__builtin_bit_cast(half2_t, w),
                                  __builtin_bit_cast(half2_t, h), acc, false);
#else
    half2_t a = __builtin_bit_cast(half2_t, w);
    half2_t b = __builtin_bit_cast(half2_t, h);
    return acc + (float)a.x * (float)b.x + (float)a.y * (float)b.y;
#endif
}
__device__ __forceinline__ uint packh2(float a, float b) {
    ushort u0 = __builtin_bit_cast(ushort, (_Float16)a);
    ushort u1 = __builtin_bit_cast(ushort, (_Float16)b);
    return (uint)u0 | ((uint)u1 << 16);
}
// e5m2 byte pair with round-to-nearest (weights are far from fp16 overflow,
// so +0x80 cannot carry into the sign or reach the inf encoding).
__device__ __forceinline__ ushort e5pair(float a, float b) {
    uint ua = (uint)__builtin_bit_cast(ushort, (_Float16)a);
    uint ub = (uint)__builtin_bit_cast(ushort, (_Float16)b);
    uint ba = ((ua + 0x80u) >> 8) & 0xFFu;
    uint bb = ((ub + 0x80u) >> 8) & 0xFFu;
    return (ushort)(ba | (bb << 8));
}

// ---- preprocessor repetition ------------------------------------------------
#define R28(X) \
  X(0) X(1) X(2) X(3) X(4) X(5) X(6) X(7) \
  X(8) X(9) X(10) X(11) X(12) X(13) X(14) X(15) \
  X(16) X(17) X(18) X(19) X(20) X(21) X(22) X(23) \
  X(24) X(25) X(26) X(27)

// h-pair lane map: pair p in [0,64) -> r0 lane p; p in [64,128) -> r1 lane
// p-64. REG covers pairs 0..27, LDS 28..103, STREAM 104..127.
#define WDECL(m) uint wA##m, wB##m;
#define WLOAD(m) wA##m = wreg[(2 * (m)) * 512 + tid]; \
                 wB##m = wreg[(2 * (m) + 1) * 512 + tid];
#define WSTEP(m) { \
    uint hp = (uint)__builtin_amdgcn_readlane((int)r0, (m)); \
    aA = dot2f(wA##m, hp, aA); \
    aB = dot2f(wB##m, hp, aB); }

// e5m2 consume: u = [b0 b1 b2 b3] = [A_k0, A_k1, B_k0, B_k1] (byte 0 = LSB).
// perm(u, 0, 0x05000400): result = [u.b1, 0, u.b0, 0] bytes 3..0 -> half2
// {A_k0<<8, A_k1<<8} = exact fp16 pair. Zero source operand (not constant
// selectors) for robustness.
#define LC1(u, p) { \
    uint hp_ = (uint)__builtin_amdgcn_readlane((int)((p) < 64 ? r0 : r1), (p) & 63); \
    uint wa_ = __builtin_amdgcn_perm((u), 0u, 0x05000400u); \
    uint wb_ = __builtin_amdgcn_perm((u), 0u, 0x07000600u); \
    aA = dot2f(wa_, hp_, aA); \
    aB = dot2f(wb_, hp_, aB); }
#define LCONS8(dv, i) \
    LC1(dv.x, 28 + 4 * (i)) LC1(dv.y, 29 + 4 * (i)) \
    LC1(dv.z, 30 + 4 * (i)) LC1(dv.w, 31 + 4 * (i))
#define SCONS8(sv, g2) \
    LC1(sv.x, 104 + 4 * (g2)) LC1(sv.y, 105 + 4 * (g2)) \
    LC1(sv.z, 106 + 4 * (g2)) LC1(sv.w, 107 + 4 * (g2))
#define LLOAD(dv, i) dv = lw4[(i) * 512 + tid];
#define SISS(sv, g2) sv = wstr4[(g2) * 512 + tid];

// ---------------------------------------------------------------------------
// zero_kernel: zero loss, preds, and feats rows with t >= len (masked region).
// ---------------------------------------------------------------------------
__global__ __launch_bounds__(256) void zero_kernel(float* __restrict__ out,
                                                   const int* __restrict__ lens) {
    int bid = blockIdx.x;
    if (bid < 65536) {
        int g = bid * 256 + threadIdx.x;
        int row = g >> 9;
        int t = row & 511;
        int b = row >> 9;
        if (t >= lens[b]) out[32769 + g] = 0.0f;
    } else if (bid < 65536 + 128) {
        int p = (bid - 65536) * 256 + threadIdx.x;
        out[1 + p] = 0.0f;
    } else if (threadIdx.x == 0) {
        out[0] = 0.0f;
    }
}

// ---------------------------------------------------------------------------
// pack_kernel: W_hh (4H,H) fp32 -> three tiers. Flat uint id per dir:
// m = id>>10 (k-pair 0..127), r = id&1023, x = r>>9 (gate half), tl = r&511.
// Thread tl=2j+s owns gates q=2s+x of hidden j.
//   m<28      fp16: wreg[(2m+x)*512 + tl] = packh2
//   28<=m<104 e5m2: mL=m-28, i=mL>>2, c=mL&3; ushort (x half) of uint
//             (i*512+tl)*4+c in wlds
//   m>=104    e5m2: mS=m-104, g=mS>>2, c=mS&3; same scheme in wstr
// grid = 1024 x 256 covers 2 dirs x 131072.
// ---------------------------------------------------------------------------
__global__ __launch_bounds__(256) void pack_kernel(const float* __restrict__ WF,
                                                   const float* __restrict__ WB,
                                                   uint* __restrict__ wregF,
                                                   uint* __restrict__ wregB,
                                                   uint* __restrict__ wldsF,
                                                   uint* __restrict__ wldsB,
                                                   uint* __restrict__ wstrF,
                                                   uint* __restrict__ wstrB) {
    int id = blockIdx.x * 256 + threadIdx.x;   // 0..262143
    const float* W = WF; uint* wr = wregF; uint* wl = wldsF; uint* wsp = wstrF;
    if (id >= 131072) { id -= 131072; W = WB; wr = wregB; wl = wldsB; wsp = wstrB; }
    int m = id >> 10;
    int r = id & 1023;
    int x = r >> 9;
    int tl = r & 511;
    int j = tl >> 1, s = tl & 1;
    int q = (s << 1) + x;
    const float* row = W + ((size_t)((q << 8) + j) << 8);
    float w0 = row[2 * m], w1 = row[2 * m + 1];
    if (m < 28) {
        wr[((m << 1) + x) * 512 + tl] = packh2(w0, w1);
    } else if (m < 104) {
        int mL = m - 28;
        int i = mL >> 2, c = mL & 3;
        size_t uidx = ((size_t)(i * 512 + tl) << 2) + c;
        reinterpret_cast<ushort*>(wl)[uidx * 2 + x] = e5pair(w0, w1);
    } else {
        int mS = m - 104;
        int g2 = mS >> 2, c = mS & 3;
        size_t uidx = ((size_t)(g2 * 512 + tl) << 2) + c;
        reinterpret_cast<ushort*>(wsp)[uidx * 2 + x] = e5pair(w0, w1);
    }
}

// ---------------------------------------------------------------------------
// wih_pack_kernel: Wih fp32 -> fp16 k-pair packed, indexed by interleaved
// output column: wih16[col*128 + p], perm(col) = (col&3)*256 + (col>>2).
// ---------------------------------------------------------------------------
__global__ __launch_bounds__(256) void wih_pack_kernel(const float* __restrict__ WihF,
                                                       const float* __restrict__ WihB,
                                                       uint* __restrict__ w16F,
                                                       uint* __restrict__ w16B) {
    int id = blockIdx.x * 256 + threadIdx.x;   // 0..262143
    const float* W = WihF; uint* dst = w16F;
    if (id >= 131072) { id -= 131072; W = WihB; dst = w16B; }
    int col = id >> 7;
    int p = id & 127;
    int perm = ((col & 3) << 8) + (col >> 2);
    const float* row = W + ((size_t)perm << 8);
    dst[(col << 7) + p] = packh2(row[2 * p], row[2 * p + 1]);
}

// ---------------------------------------------------------------------------
// gemm_gx: fp16-pair dot2 GEMM. gx_il[row][col] = emb[row].Wih[perm(col)] +
// bias[perm(col)]. 64x64 tile, 32 k per iter, 4x4/thread. Skips masked tiles.
// grid = (512, 16)
// ---------------------------------------------------------------------------
__global__ __launch_bounds__(256) void gemm_gx_kernel(const int* __restrict__ widx,
                                                      const int* __restrict__ lens,
                                                      const float* __restrict__ wvec,
                                                      const uint* __restrict__ wih16,
                                                      const float* __restrict__ bias,
                                                      _Float16* __restrict__ gx) {
    int row0 = blockIdx.x * 64;
    int b = row0 >> 9;
    int t0 = row0 & 511;
    if (t0 >= lens[b]) return;
    int n0 = blockIdx.y * 64;

    __shared__ __align__(16) uint As[16][68];
    __shared__ __align__(16) uint Bs[16][68];
    __shared__ int aoff[64];

    int tid = threadIdx.x;
    if (tid < 64) aoff[tid] = widx[row0 + tid] << 8;
    __syncthreads();

    float acc[4][4] = {};
    int tn = tid & 15, tm = tid >> 4;

    for (int k0p = 0; k0p < 128; k0p += 16) {
#pragma unroll
        for (int p = 0; p < 4; ++p) {
            int lin = p * 256 + tid;
            int kp = lin & 15, m = lin >> 4;
            const float2 av = *reinterpret_cast<const float2*>(
                &wvec[aoff[m] + ((k0p + kp) << 1)]);
            As[kp][m] = packh2(av.x, av.y);
            Bs[kp][m] = wih16[((n0 + m) << 7) + k0p + kp];
        }
        __syncthreads();
#pragma unroll
        for (int kp = 0; kp < 16; ++kp) {
            uint4 a4 = *reinterpret_cast<const uint4*>(&As[kp][tm * 4]);
            uint4 b4 = *reinterpret_cast<const uint4*>(&Bs[kp][tn * 4]);
            uint am[4] = {a4.x, a4.y, a4.z, a4.w};
            uint bn[4] = {b4.x, b4.y, b4.z, b4.w};
#pragma unroll
            for (int i = 0; i < 4; ++i)
#pragma unroll
                for (int j = 0; j < 4; ++j) acc[i][j] = dot2f(am[i], bn[j], acc[i][j]);
        }
        __syncthreads();
    }

#pragma unroll
    for (int i = 0; i < 4; ++i) {
        int row = row0 + tm * 4 + i;
        ushort u[4];
#pragma unroll
        for (int j = 0; j < 4; ++j) {
            int col = n0 + tn * 4 + j;
            int perm = ((col & 3) << 8) + (col >> 2);
            u[j] = __builtin_bit_cast(ushort, (_Float16)(acc[i][j] + bias[perm]));
        }
        uint2 st;
        st.x = (uint)u[0] | ((uint)u[1] << 16);
        st.y = (uint)u[2] | ((uint)u[3] << 16);
        *reinterpret_cast<uint2*>(&gx[row * 1024 + n0 + tn * 4]) = st;
    }
}

// ---------------------------------------------------------------------------
// lstm_kernel: one block per (b, dir); 512 threads. Thread 2j+s owns gate
// rows {2s, 2s+1} of hidden j. Three-tier W: 28 pairs fp16 in regs,
// 76 pairs e5m2 in LDS (5-deep ds_read rotation), 24 pairs e5m2 streamed
// (6 uint4/thread, all issued pre-barrier -> full-step latency cover).
// Raw asm barrier (lgkmcnt only) keeps stream prefetch + feats store in
// flight across the step boundary.
// ---------------------------------------------------------------------------
__global__ __launch_bounds__(512)
void lstm_kernel(const _Float16* __restrict__ gx0,
                 const _Float16* __restrict__ gx1,
                 const uint* __restrict__ wreg0,
                 const uint* __restrict__ wreg1,
                 const uint* __restrict__ wlds0,
                 const uint* __restrict__ wlds1,
                 const uint* __restrict__ wstr0,
                 const uint* __restrict__ wstr1,
                 const int* __restrict__ lens,
                 float* __restrict__ feats) {
    int dir = blockIdx.x & 1;
    int b = blockIdx.x >> 1;
    const uint* gxu = reinterpret_cast<const uint*>(dir ? gx1 : gx0) + ((size_t)(b << 9) << 9);
    const uint* wreg = dir ? wreg1 : wreg0;
    const uint4* wlds4 = reinterpret_cast<const uint4*>(dir ? wlds1 : wlds0);
    const uint4* wstr4 = reinterpret_cast<const uint4*>(dir ? wstr1 : wstr0);
    int len = lens[b];
    int tid = threadIdx.x;
    int lane = tid & 63;
    int sg = tid & 1;

    __shared__ __align__(16) uint4 lw4[WLDS_U4];     // 152 KB LDS W chunk
    __shared__ __align__(16) uint hpair[2][128];     // fp16-pair h, dbuf

    for (int i = tid; i < WLDS_U4; i += 512) lw4[i] = wlds4[i];

    R28(WDECL)            // uint wA0..wA27, wB0..wB27 — named scalars
    R28(WLOAD)
    __syncthreads();

    float c = 0.0f;
    uint r0 = 0, r1 = 0;
    int pp = 0;

    int t0i = dir ? (len - 1) : 0;
    uint g = gxu[(t0i << 9) + tid];

    uint4 s0, s1, s2, s3, s4, s5;  // stream landing (24 regs, t-invariant src)
    uint4 d0, d1, d2, d3, d4;      // LDS pipeline regs (5-deep)

    // prologue: all 6 stream groups in flight into the loop
    SISS(s0, 0) SISS(s1, 1) SISS(s2, 2) SISS(s3, 3) SISS(s4, 4) SISS(s5, 5)

    for (int tp = 0; tp < len; ++tp) {
        int t = dir ? (len - 1 - tp) : tp;
        int tnn = dir ? (len - 2 - tp) : (tp + 1);
        tnn = tnn < 0 ? 0 : (tnn >= len ? len - 1 : tnn);
        uint gnext = gxu[(tnn << 9) + tid];

        half2_t gv = __builtin_bit_cast(half2_t, g);
        float aA = (float)gv.x;
        float aB = (float)gv.y;

        // fill LDS pipeline 5 deep
        LLOAD(d0, 0) LLOAD(d1, 1) LLOAD(d2, 2) LLOAD(d3, 3) LLOAD(d4, 4)
        WSTEP(0)  WSTEP(1)  WSTEP(2)  WSTEP(3)  WSTEP(4)  WSTEP(5)
        WSTEP(6)  WSTEP(7)  WSTEP(8)  WSTEP(9)  WSTEP(10) WSTEP(11)
        WSTEP(12) WSTEP(13)
        SCONS8(s0, 0) SCONS8(s1, 1)
        WSTEP(14) WSTEP(15) WSTEP(16) WSTEP(17) WSTEP(18) WSTEP(19)
        WSTEP(20) WSTEP(21) WSTEP(22) WSTEP(23) WSTEP(24) WSTEP(25)
        WSTEP(26) WSTEP(27)
        LCONS8(d0, 0)  LLOAD(d0, 5)
        LCONS8(d1, 1)  LLOAD(d1, 6)
        LCONS8(d2, 2)  LLOAD(d2, 7)
        SCONS8(s2, 2)
        LCONS8(d3, 3)  LLOAD(d3, 8)
        LCONS8(d4, 4)  LLOAD(d4, 9)
        LCONS8(d0, 5)  LLOAD(d0, 10)
        SCONS8(s3, 3)
        LCONS8(d1, 6)  LLOAD(d1, 11)
        LCONS8(d2, 7)  LLOAD(d2, 12)
        LCONS8(d3, 8)  LLOAD(d3, 13)
        SCONS8(s4, 4)
        LCONS8(d4, 9)  LLOAD(d4, 14)
        LCONS8(d0, 10) LLOAD(d0, 15)
        LCONS8(d1, 11) LLOAD(d1, 16)
        SCONS8(s5, 5)
        LCONS8(d2, 12) LLOAD(d2, 17)
        LCONS8(d3, 13) LLOAD(d3, 18)
        LCONS8(d4, 14)
        LCONS8(d0, 15)
        LCONS8(d1, 16)
        LCONS8(d2, 17)
        LCONS8(d3, 18)

        // s=0: pA=sigm(i), pB=sigm(f) ; s=1: pA=tanh(g), pB=sigm(o)
        float y = sg ? aA + aA : aA;
        float sgm = __fdividef(1.0f, 1.0f + __expf(-y));
        float pA = sg ? sgm + sgm - 1.0f : sgm;
        float pB = sigm(aB);

        float oA = __shfl_xor(pA, 1);
        float oB = __shfl_xor(pB, 1);
        float si = sg ? oA : pA;
        float sf = sg ? oB : pB;
        float tg = sg ? pA : oA;
        float so = sg ? pB : oB;

        c = sf * c + si * tg;
        float h = so * tanh_fast(c);

        if (!sg) {
            reinterpret_cast<ushort*>(hpair[pp])[tid >> 1] =
                __builtin_bit_cast(ushort, (_Float16)h);
        }
        // re-issue next step's stream (t-invariant addrs) BEFORE the barrier;
        // they stay in flight across it (raw barrier: no vmcnt drain).
        SISS(s0, 0) SISS(s1, 1) SISS(s2, 2) SISS(s3, 3) SISS(s4, 4) SISS(s5, 5)
        asm volatile("s_waitcnt lgkmcnt(0)\n\ts_barrier" ::: "memory");
        // global store after the barrier: fire-and-forget, no reader until
        // kernel end; never drained inside the loop.
        if (!sg) {
            feats[(size_t)(((b << 9) + t)) * 512 + (dir << 8) + (tid >> 1)] = h;
        }
        r0 = hpair[pp][lane];
        r1 = hpair[pp][64 + lane];
        pp ^= 1;
        g = gnext;
    }
}

// ---------------------------------------------------------------------------
// emis_kernel: emissions[b,t,k] = feats[b,t,:] . W_out[k,:] + b_out[k]
// ---------------------------------------------------------------------------
__global__ __launch_bounds__(64) void emis_kernel(const float* __restrict__ feats,
                                                  const float* __restrict__ Wout,
                                                  const float* __restrict__ bout,
                                                  const int* __restrict__ lens,
                                                  float* __restrict__ emis) {
    int r = blockIdx.x;
    int b = r >> 9, t = r & 511;
    if (t >= lens[b]) return;
    int lane = threadIdx.x;
    const float* fr = feats + (size_t)r * 512;
    float f[8];
#pragma unroll
    for (int i = 0; i < 8; ++i) f[i] = fr[i * 64 + lane];
#pragma unroll
    for (int k = 0; k < 9; ++k) {
        float p = 0.0f;
#pragma unroll
        for (int i = 0; i < 8; ++i) p = fmaf(f[i], Wout[k * 512 + i * 64 + lane], p);
#pragma unroll
        for (int off = 32; off; off >>= 1) p += __shfl_down(p, off);
        if (lane == 0) emis[r * 9 + k] = p + bout[k];
    }
}

// ---------------------------------------------------------------------------
// crf_kernel: alpha recursion + viterbi + backtrace + numerator + loss.
// ---------------------------------------------------------------------------
__global__ __launch_bounds__(64) void crf_kernel(const float* __restrict__ emis,
                                                 const int* __restrict__ lens,
                                                 const int* __restrict__ labels,
                                                 const float* __restrict__ start_trans,
                                                 const float* __restrict__ end_trans,
                                                 const float* __restrict__ trans,
                                                 float* __restrict__ out) {
    int b = blockIdx.x;
    int len = lens[b];
    int lane = threadIdx.x;
    __shared__ float alpha[9], vit[9];
    __shared__ unsigned char hist[512 * 9];
    const float* eb = emis + b * 512 * 9;
    const int* lb = labels + b * 512;

    float tr[9];
    if (lane < 9) {
#pragma unroll
        for (int i = 0; i < 9; ++i) tr[i] = trans[i * 9 + lane];
        float s0 = start_trans[lane] + eb[lane];
        alpha[lane] = s0;
        vit[lane] = s0;
    }
    __syncthreads();

    for (int t = 1; t < len; ++t) {
        float na = 0.0f, nv = 0.0f;
        if (lane < 9) {
            float e = eb[t * 9 + lane];
            float a[9];
#pragma unroll
            for (int i = 0; i < 9; ++i) a[i] = alpha[i] + tr[i];
            float m = a[0];
#pragma unroll
            for (int i = 1; i < 9; ++i) m = fmaxf(m, a[i]);
            float s = 0.0f;
#pragma unroll
            for (int i = 0; i < 9; ++i) s += __expf(a[i] - m);
            na = m + __logf(s) + e;
            float bv = vit[0] + tr[0];
            int bi = 0;
#pragma unroll
            for (int i = 1; i < 9; ++i) {
                float x = vit[i] + tr[i];
                if (x > bv) { bv = x; bi = i; }
            }
            nv = bv + e;
            hist[t * 9 + lane] = (unsigned char)bi;
        }
        __syncthreads();
        if (lane < 9) { alpha[lane] = na; vit[lane] = nv; }
        __syncthreads();
    }

    float part = 0.0f;
    for (int t = 1 + lane; t < len; t += 64) {
        int yp = lb[t - 1], y = lb[t];
        part += trans[yp * 9 + y] + eb[t * 9 + y];
    }
#pragma unroll
    for (int off = 32; off; off >>= 1) part += __shfl_down(part, off);

    if (lane == 0) {
        int y0 = lb[0];
        float num = start_trans[y0] + eb[y0] + part + end_trans[lb[len - 1]];
        float m = alpha[0] + end_trans[0];
        for (int j = 1; j < 9; ++j) m = fmaxf(m, alpha[j] + end_trans[j]);
        float s = 0.0f;
        for (int j = 0; j < 9; ++j) s += __expf(alpha[j] + end_trans[j] - m);
        float denom = m + __logf(s);
        atomicAdd(out, (denom - num) * (1.0f / 64.0f));

        float bm = vit[0] + end_trans[0];
        int cur = 0;
        for (int j = 1; j < 9; ++j) {
            float x = vit[j] + end_trans[j];
            if (x > bm) { bm = x; cur = j; }
        }
        float* preds = out + 1 + b * 512;
        preds[len - 1] = (float)cur;
        for (int t = len - 1; t >= 1; --t) {
            cur = hist[t * 9 + cur];
            preds[t - 1] = (float)cur;
        }
    }
}

// ---------------------------------------------------------------------------
extern "C" void kernel_launch(void* const* d_in, const int* in_sizes, int n_in,
                              void* d_out, int out_size, void* d_ws, size_t ws_size,
                              hipStream_t stream) {
    const int* widx = (const int*)d_in[0];
    const int* lens = (const int*)d_in[1];
    const int* labels = (const int*)d_in[2];
    const float* wvec = (const float*)d_in[3];
    const float* WihF = (const float*)d_in[4];
    const float* WhhF = (const float*)d_in[5];
    const float* bF = (const float*)d_in[6];
    const float* WihB = (const float*)d_in[7];
    const float* WhhB = (const float*)d_in[8];
    const float* bB = (const float*)d_in[9];
    const float* Wout = (const float*)d_in[10];
    const float* bout = (const float*)d_in[11];
    const float* start_trans = (const float*)d_in[12];
    const float* end_trans = (const float*)d_in[13];
    const float* trans9 = (const float*)d_in[14];
    float* out = (float*)d_out;
    char* ws = (char*)d_ws;

    // workspace layout (bytes)
    _Float16* gxF = (_Float16*)(ws);                        // 67,108,864
    _Float16* gxB = (_Float16*)(ws + 67108864);             // 67,108,864
    uint* wregF   = (uint*)(ws + 134217728);                // 114,688
    uint* wregB   = (uint*)(ws + 134332416);                // 114,688
    uint* wldsF   = (uint*)(ws + 134447104);                // 155,648
    uint* wldsB   = (uint*)(ws + 134602752);                // 155,648
    uint* wstrF   = (uint*)(ws + 134758400);                // 49,152
    uint* wstrB   = (uint*)(ws + 134807552);                // 49,152
    // wih16F/B live only before lstm; emis written after lstm -> safe alias
    uint* wih16F  = (uint*)(ws + 134856704);                // 524,288
    uint* wih16B  = (uint*)(ws + 135380992);                // 524,288
    float* emis   = (float*)(ws + 134856704);               // 1,179,648 (alias)
    (void)in_sizes; (void)n_in; (void)out_size; (void)ws_size;

    float* feats = out + 1 + 32768;   // feats output region (B,T,512) fp32

    zero_kernel<<<65665, 256, 0, stream>>>(out, lens);
    pack_kernel<<<1024, 256, 0, stream>>>(WhhF, WhhB, wregF, wregB, wldsF, wldsB,
                                          wstrF, wstrB);
    wih_pack_kernel<<<1024, 256, 0, stream>>>(WihF, WihB, wih16F, wih16B);

    dim3 ggrid(512, 16);
    gemm_gx_kernel<<<ggrid, 256, 0, stream>>>(widx, lens, wvec, wih16F, bF, gxF);
    gemm_gx_kernel<<<ggrid, 256, 0, stream>>>(widx, lens, wvec, wih16B, bB, gxB);

    lstm_kernel<<<128, 512, 0, stream>>>(gxF, gxB, wregF, wregB, wldsF, wldsB,
                                         wstrF, wstrB, lens, feats);

    emis_kernel<<<32768, 64, 0, stream>>>(feats, Wout, bout, lens, emis);
    crf_kernel<<<64, 64, 0, stream>>>(emis, lens, labels, start_trans, end_trans, trans9, out);
}

// Round 10
// 1693.007 us; speedup vs baseline: 1.1099x; 1.1099x over previous
//
#include <hip/hip_runtime.h>
#include <hip/hip_bf16.h>
#include <math.h>

#ifndef __has_builtin
#define __has_builtin(x) 0
#endif

typedef unsigned int uint;
typedef unsigned short ushort;
typedef _Float16 half2_t __attribute__((ext_vector_type(2)));

// Problem constants: B=64, T=512, V=30000, E=256, H=256, K=9. 4H = 1024.
//
// Model (rounds 5-9): r7 (993us) was VMEM-BW-bound: step 4660 cyc ~= 256KB
// stream / 60 B/cyc/CU (4370) + 290 — VALU/LDS already overlap under it.
// r9's all-e5m2 rebuild broke the VGPR budget (VGPR 88 < live-set 120 ->
// compiler evicted W, hidden L2 reloads, 1256us). THIS ROUND: r7 skeleton
// EXACTLY (live set identical, measured 116 VGPR), one change: the 64
// streamed k-pairs are e5m2 (fp16 top byte; decode = 2 v_perm_b32/pair,
// validated correct in r9). Stream 256KB -> 128KB/block/step.
// Tiers: REG 26 pairs fp16 (52 uints) / LDS 38 pairs fp16 (19 uint4-groups,
// 152KB) / STREAM 64 pairs e5m2 (16 uint4-groups, 128KB).
// New budget: VMEM 2185, VALU ~2370, LDS 1824 -> VALU-bound ~2400 cyc/step.
#define WREG_UINTS (26 * 2 * 512)          // 26624
#define WLDS_U4    (19 * 512)              // 9728 uint4 = 155648 B
#define WSTR_U4    (16 * 512)              // 8192 uint4 = 131072 B

__device__ __forceinline__ float sigm(float x) {
    return __fdividef(1.0f, 1.0f + __expf(-x));
}
__device__ __forceinline__ float tanh_fast(float x) {
    float sg = __fdividef(1.0f, 1.0f + __expf(-2.0f * x));
    return sg + sg - 1.0f;
}
__device__ __forceinline__ float dot2f(uint w, uint h, float acc) {
#if __has_builtin(__builtin_amdgcn_fdot2)
    return __builtin_amdgcn_fdot2(__builtin_bit_cast(half2_t, w),
                                  __builtin_bit_cast(half2_t, h), acc, false);
#else
    half2_t a = __builtin_bit_cast(half2_t, w);
    half2_t b = __builtin_bit_cast(half2_t, h);
    return acc + (float)a.x * (float)b.x + (float)a.y * (float)b.y;
#endif
}
__device__ __forceinline__ uint packh2(float a, float b) {
    ushort u0 = __builtin_bit_cast(ushort, (_Float16)a);
    ushort u1 = __builtin_bit_cast(ushort, (_Float16)b);
    return (uint)u0 | ((uint)u1 << 16);
}
// e5m2 byte pair with round-to-nearest (weights are far from fp16 overflow,
// so +0x80 cannot carry into the sign or reach the inf encoding).
__device__ __forceinline__ ushort e5pair(float a, float b) {
    uint ua = (uint)__builtin_bit_cast(ushort, (_Float16)a);
    uint ub = (uint)__builtin_bit_cast(ushort, (_Float16)b);
    uint ba = ((ua + 0x80u) >> 8) & 0xFFu;
    uint bb = ((ub + 0x80u) >> 8) & 0xFFu;
    return (ushort)(ba | (bb << 8));
}

// ---- preprocessor repetition ------------------------------------------------
#define R26(X) \
  X(0) X(1) X(2) X(3) X(4) X(5) X(6) X(7) \
  X(8) X(9) X(10) X(11) X(12) X(13) X(14) X(15) \
  X(16) X(17) X(18) X(19) X(20) X(21) X(22) X(23) \
  X(24) X(25)

#define WDECL(m) uint wA##m, wB##m;
#define WLOAD(m) wA##m = wreg[(2 * (m)) * 512 + tid]; \
                 wB##m = wreg[(2 * (m) + 1) * 512 + tid];
#define WSTEP(m) { \
    uint hp = (uint)__builtin_amdgcn_readlane((int)r0, (m)); \
    aA = dot2f(wA##m, hp, aA); \
    aB = dot2f(wB##m, hp, aB); }

// LDS tier (fp16): group i (0..18) = pairs 26+2i, 27+2i (both r0 lanes).
#define LLOAD(dv, i) dv = lw4[(i) * 512 + tid];
#define LCONS(dv, i) { \
    uint hp0 = (uint)__builtin_amdgcn_readlane((int)r0, 26 + 2 * (i)); \
    uint hp1 = (uint)__builtin_amdgcn_readlane((int)r0, 27 + 2 * (i)); \
    aA = dot2f(dv.x, hp0, aA); \
    aB = dot2f(dv.y, hp0, aB); \
    aA = dot2f(dv.z, hp1, aA); \
    aB = dot2f(dv.w, hp1, aB); }

// Stream tier (e5m2): uint = 1 k-pair, bytes [A_k0, A_k1, B_k0, B_k1].
// perm sel 0x05000400 -> {u.b1<<8 | 0}hi,{u.b0<<8 | 0}lo = fp16 pair of A;
// 0x07000600 -> fp16 pair of B. Pair p in [64,128) -> r1 lane p-64.
#define LC1(u, p) { \
    uint hp_ = (uint)__builtin_amdgcn_readlane((int)r1, (p) - 64); \
    uint wa_ = __builtin_amdgcn_perm((u), 0u, 0x05000400u); \
    uint wb_ = __builtin_amdgcn_perm((u), 0u, 0x07000600u); \
    aA = dot2f(wa_, hp_, aA); \
    aB = dot2f(wb_, hp_, aB); }
// uint4 group g (0..15) = pairs 64+4g .. 67+4g.
#define SCONS8(sv, g2) \
    LC1(sv.x, 64 + 4 * (g2)) LC1(sv.y, 65 + 4 * (g2)) \
    LC1(sv.z, 66 + 4 * (g2)) LC1(sv.w, 67 + 4 * (g2))
// batch j (0..3) = groups 4j..4j+3 (16 pairs)
#define SISSUE(s0_, s1_, s2_, s3_, j) { \
    s0_ = wstr4[(4 * (j) + 0) * 512 + tid]; \
    s1_ = wstr4[(4 * (j) + 1) * 512 + tid]; \
    s2_ = wstr4[(4 * (j) + 2) * 512 + tid]; \
    s3_ = wstr4[(4 * (j) + 3) * 512 + tid]; }
#define SCONSB(s0_, s1_, s2_, s3_, j) \
    SCONS8(s0_, 4 * (j) + 0) SCONS8(s1_, 4 * (j) + 1) \
    SCONS8(s2_, 4 * (j) + 2) SCONS8(s3_, 4 * (j) + 3)

// ---------------------------------------------------------------------------
// zero_kernel: zero loss, preds, and feats rows with t >= len (masked region).
// ---------------------------------------------------------------------------
__global__ __launch_bounds__(256) void zero_kernel(float* __restrict__ out,
                                                   const int* __restrict__ lens) {
    int bid = blockIdx.x;
    if (bid < 65536) {
        int g = bid * 256 + threadIdx.x;
        int row = g >> 9;
        int t = row & 511;
        int b = row >> 9;
        if (t >= lens[b]) out[32769 + g] = 0.0f;
    } else if (bid < 65536 + 128) {
        int p = (bid - 65536) * 256 + threadIdx.x;
        out[1 + p] = 0.0f;
    } else if (threadIdx.x == 0) {
        out[0] = 0.0f;
    }
}

// ---------------------------------------------------------------------------
// pack_kernel: W_hh (4H,H) fp32 -> three tiers. Flat uint id per dir:
// m = id>>10 (k-pair 0..127), r = id&1023, x = r>>9 (gate half), tl = r&511.
// Thread tl=2j+s owns gates q=2s+x of hidden j.
//   m<26      fp16: wreg[(2m+x)*512 + tl] = packh2
//   26<=m<64  fp16: mL=m-26: wlds[((mL>>1)*512 + tl)*4 + (mL&1)*2+x]
//   m>=64     e5m2: mS=m-64, g=mS>>2, c=mS&3; ushort x of uint
//             (g*512+tl)*4+c in wstr
// grid = 1024 x 256 covers 2 dirs x 131072.
// ---------------------------------------------------------------------------
__global__ __launch_bounds__(256) void pack_kernel(const float* __restrict__ WF,
                                                   const float* __restrict__ WB,
                                                   uint* __restrict__ wregF,
                                                   uint* __restrict__ wregB,
                                                   uint* __restrict__ wldsF,
                                                   uint* __restrict__ wldsB,
                                                   uint* __restrict__ wstrF,
                                                   uint* __restrict__ wstrB) {
    int id = blockIdx.x * 256 + threadIdx.x;   // 0..262143
    const float* W = WF; uint* wr = wregF; uint* wl = wldsF; uint* wsp = wstrF;
    if (id >= 131072) { id -= 131072; W = WB; wr = wregB; wl = wldsB; wsp = wstrB; }
    int m = id >> 10;
    int r = id & 1023;
    int x = r >> 9;
    int tl = r & 511;
    int j = tl >> 1, s = tl & 1;
    int q = (s << 1) + x;
    const float* row = W + ((size_t)((q << 8) + j) << 8);
    float w0 = row[2 * m], w1 = row[2 * m + 1];
    if (m < 26) {
        wr[((m << 1) + x) * 512 + tl] = packh2(w0, w1);
    } else if (m < 64) {
        int mL = m - 26;
        wl[(((mL >> 1) << 9) + tl) * 4 + ((mL & 1) << 1) + x] = packh2(w0, w1);
    } else {
        int mS = m - 64;
        int g2 = mS >> 2, c = mS & 3;
        size_t uidx = ((size_t)(g2 * 512 + tl) << 2) + c;
        reinterpret_cast<ushort*>(wsp)[uidx * 2 + x] = e5pair(w0, w1);
    }
}

// ---------------------------------------------------------------------------
// wih_pack_kernel: Wih fp32 -> fp16 k-pair packed, indexed by interleaved
// output column: wih16[col*128 + p], perm(col) = (col&3)*256 + (col>>2).
// ---------------------------------------------------------------------------
__global__ __launch_bounds__(256) void wih_pack_kernel(const float* __restrict__ WihF,
                                                       const float* __restrict__ WihB,
                                                       uint* __restrict__ w16F,
                                                       uint* __restrict__ w16B) {
    int id = blockIdx.x * 256 + threadIdx.x;   // 0..262143
    const float* W = WihF; uint* dst = w16F;
    if (id >= 131072) { id -= 131072; W = WihB; dst = w16B; }
    int col = id >> 7;
    int p = id & 127;
    int perm = ((col & 3) << 8) + (col >> 2);
    const float* row = W + ((size_t)perm << 8);
    dst[(col << 7) + p] = packh2(row[2 * p], row[2 * p + 1]);
}

// ---------------------------------------------------------------------------
// gemm_gx: fp16-pair dot2 GEMM. gx_il[row][col] = emb[row].Wih[perm(col)] +
// bias[perm(col)]. 64x64 tile, 32 k per iter, 4x4/thread. Skips masked tiles.
// grid = (512, 16)
// ---------------------------------------------------------------------------
__global__ __launch_bounds__(256) void gemm_gx_kernel(const int* __restrict__ widx,
                                                      const int* __restrict__ lens,
                                                      const float* __restrict__ wvec,
                                                      const uint* __restrict__ wih16,
                                                      const float* __restrict__ bias,
                                                      _Float16* __restrict__ gx) {
    int row0 = blockIdx.x * 64;
    int b = row0 >> 9;
    int t0 = row0 & 511;
    if (t0 >= lens[b]) return;
    int n0 = blockIdx.y * 64;

    __shared__ __align__(16) uint As[16][68];
    __shared__ __align__(16) uint Bs[16][68];
    __shared__ int aoff[64];

    int tid = threadIdx.x;
    if (tid < 64) aoff[tid] = widx[row0 + tid] << 8;
    __syncthreads();

    float acc[4][4] = {};
    int tn = tid & 15, tm = tid >> 4;

    for (int k0p = 0; k0p < 128; k0p += 16) {
#pragma unroll
        for (int p = 0; p < 4; ++p) {
            int lin = p * 256 + tid;
            int kp = lin & 15, m = lin >> 4;
            const float2 av = *reinterpret_cast<const float2*>(
                &wvec[aoff[m] + ((k0p + kp) << 1)]);
            As[kp][m] = packh2(av.x, av.y);
            Bs[kp][m] = wih16[((n0 + m) << 7) + k0p + kp];
        }
        __syncthreads();
#pragma unroll
        for (int kp = 0; kp < 16; ++kp) {
            uint4 a4 = *reinterpret_cast<const uint4*>(&As[kp][tm * 4]);
            uint4 b4 = *reinterpret_cast<const uint4*>(&Bs[kp][tn * 4]);
            uint am[4] = {a4.x, a4.y, a4.z, a4.w};
            uint bn[4] = {b4.x, b4.y, b4.z, b4.w};
#pragma unroll
            for (int i = 0; i < 4; ++i)
#pragma unroll
                for (int j = 0; j < 4; ++j) acc[i][j] = dot2f(am[i], bn[j], acc[i][j]);
        }
        __syncthreads();
    }

#pragma unroll
    for (int i = 0; i < 4; ++i) {
        int row = row0 + tm * 4 + i;
        ushort u[4];
#pragma unroll
        for (int j = 0; j < 4; ++j) {
            int col = n0 + tn * 4 + j;
            int perm = ((col & 3) << 8) + (col >> 2);
            u[j] = __builtin_bit_cast(ushort, (_Float16)(acc[i][j] + bias[perm]));
        }
        uint2 st;
        st.x = (uint)u[0] | ((uint)u[1] << 16);
        st.y = (uint)u[2] | ((uint)u[3] << 16);
        *reinterpret_cast<uint2*>(&gx[row * 1024 + n0 + tn * 4]) = st;
    }
}

// ---------------------------------------------------------------------------
// lstm_kernel: one block per (b, dir); 512 threads. Thread 2j+s owns gate
// rows {2s, 2s+1} of hidden j. r7 skeleton (proven-overlap schedule):
// 26 pairs fp16 in regs, 38 pairs fp16 in LDS (5-deep ds_read rotation),
// 64 pairs e5m2 streamed (16 uint4-groups = 128KB/step, 2 landing sets of
// 16 regs, batches b0/b1 prefetched across the barrier). Raw asm barrier
// (lgkmcnt only) keeps stream prefetch + feats store in flight.
// ---------------------------------------------------------------------------
__global__ __launch_bounds__(512)
void lstm_kernel(const _Float16* __restrict__ gx0,
                 const _Float16* __restrict__ gx1,
                 const uint* __restrict__ wreg0,
                 const uint* __restrict__ wreg1,
                 const uint* __restrict__ wlds0,
                 const uint* __restrict__ wlds1,
                 const uint* __restrict__ wstr0,
                 const uint* __restrict__ wstr1,
                 const int* __restrict__ lens,
                 float* __restrict__ feats) {
    int dir = blockIdx.x & 1;
    int b = blockIdx.x >> 1;
    const uint* gxu = reinterpret_cast<const uint*>(dir ? gx1 : gx0) + ((size_t)(b << 9) << 9);
    const uint* wreg = dir ? wreg1 : wreg0;
    const uint4* wlds4 = reinterpret_cast<const uint4*>(dir ? wlds1 : wlds0);
    const uint4* wstr4 = reinterpret_cast<const uint4*>(dir ? wstr1 : wstr0);
    int len = lens[b];
    int tid = threadIdx.x;
    int lane = tid & 63;
    int sg = tid & 1;

    __shared__ __align__(16) uint4 lw4[WLDS_U4];     // 152 KB LDS W chunk
    __shared__ __align__(16) uint hpair[2][128];     // fp16-pair h, dbuf

    for (int i = tid; i < WLDS_U4; i += 512) lw4[i] = wlds4[i];

    R26(WDECL)            // uint wA0..wA25, wB0..wB25 — named scalars
    R26(WLOAD)
    __syncthreads();

    float c = 0.0f;
    uint r0 = 0, r1 = 0;
    int pp = 0;

    int t0i = dir ? (len - 1) : 0;
    uint g = gxu[(t0i << 9) + tid];

    uint4 sA0, sA1, sA2, sA3;      // stream landing set A
    uint4 sB0, sB1, sB2, sB3;      // stream landing set B
    uint4 d0, d1, d2, d3, d4;      // LDS pipeline regs (5-deep)

    // prologue: batches b0, b1 in flight into the loop
    SISSUE(sA0, sA1, sA2, sA3, 0)
    SISSUE(sB0, sB1, sB2, sB3, 1)

    for (int tp = 0; tp < len; ++tp) {
        int t = dir ? (len - 1 - tp) : tp;
        int tnn = dir ? (len - 2 - tp) : (tp + 1);
        tnn = tnn < 0 ? 0 : (tnn >= len ? len - 1 : tnn);
        uint gnext = gxu[(tnn << 9) + tid];

        half2_t gv = __builtin_bit_cast(half2_t, g);
        float aA = (float)gv.x;
        float aB = (float)gv.y;

        // fill LDS pipeline 5 deep
        LLOAD(d0, 0) LLOAD(d1, 1) LLOAD(d2, 2) LLOAD(d3, 3) LLOAD(d4, 4)
        WSTEP(0)  WSTEP(1)  WSTEP(2)  WSTEP(3)  WSTEP(4)  WSTEP(5)
        WSTEP(6)  WSTEP(7)
        SCONSB(sA0, sA1, sA2, sA3, 0)       // b0 (in flight since prev step)
        SISSUE(sA0, sA1, sA2, sA3, 2)       // b2
        WSTEP(8)  WSTEP(9)  WSTEP(10) WSTEP(11) WSTEP(12) WSTEP(13)
        WSTEP(14) WSTEP(15) WSTEP(16)
        SCONSB(sB0, sB1, sB2, sB3, 1)       // b1
        SISSUE(sB0, sB1, sB2, sB3, 3)       // b3
        WSTEP(17) WSTEP(18) WSTEP(19) WSTEP(20) WSTEP(21) WSTEP(22)
        WSTEP(23) WSTEP(24) WSTEP(25)
        LCONS(d0, 0)  LLOAD(d0, 5)
        LCONS(d1, 1)  LLOAD(d1, 6)
        LCONS(d2, 2)  LLOAD(d2, 7)
        LCONS(d3, 3)  LLOAD(d3, 8)
        LCONS(d4, 4)  LLOAD(d4, 9)
        SCONSB(sA0, sA1, sA2, sA3, 2)       // b2 (issued ~1/2 step ago)
        LCONS(d0, 5)  LLOAD(d0, 10)
        LCONS(d1, 6)  LLOAD(d1, 11)
        LCONS(d2, 7)  LLOAD(d2, 12)
        LCONS(d3, 8)  LLOAD(d3, 13)
        LCONS(d4, 9)  LLOAD(d4, 14)
        SCONSB(sB0, sB1, sB2, sB3, 3)       // b3
        LCONS(d0, 10) LLOAD(d0, 15)
        LCONS(d1, 11) LLOAD(d1, 16)
        LCONS(d2, 12) LLOAD(d2, 17)
        LCONS(d3, 13) LLOAD(d3, 18)
        LCONS(d4, 14)
        LCONS(d0, 15) LCONS(d1, 16)
        LCONS(d2, 17) LCONS(d3, 18)

        // s=0: pA=sigm(i), pB=sigm(f) ; s=1: pA=tanh(g), pB=sigm(o)
        float y = sg ? aA + aA : aA;
        float sgm = __fdividef(1.0f, 1.0f + __expf(-y));
        float pA = sg ? sgm + sgm - 1.0f : sgm;
        float pB = sigm(aB);

        float oA = __shfl_xor(pA, 1);
        float oB = __shfl_xor(pB, 1);
        float si = sg ? oA : pA;
        float sf = sg ? oB : pB;
        float tg = sg ? pA : oA;
        float so = sg ? pB : oB;

        c = sf * c + si * tg;
        float h = so * tanh_fast(c);

        if (!sg) {
            reinterpret_cast<ushort*>(hpair[pp])[tid >> 1] =
                __builtin_bit_cast(ushort, (_Float16)h);
        }
        // prefetch next step's b0, b1 BEFORE the barrier (t-invariant addrs);
        // they stay in flight across it (raw barrier: no vmcnt drain).
        SISSUE(sA0, sA1, sA2, sA3, 0)
        SISSUE(sB0, sB1, sB2, sB3, 1)
        asm volatile("s_waitcnt lgkmcnt(0)\n\ts_barrier" ::: "memory");
        // global store after the barrier: fire-and-forget, no reader until
        // kernel end; never drained inside the loop.
        if (!sg) {
            feats[(size_t)(((b << 9) + t)) * 512 + (dir << 8) + (tid >> 1)] = h;
        }
        r0 = hpair[pp][lane];
        r1 = hpair[pp][64 + lane];
        pp ^= 1;
        g = gnext;
    }
}

// ---------------------------------------------------------------------------
// emis_kernel: emissions[b,t,k] = feats[b,t,:] . W_out[k,:] + b_out[k]
// ---------------------------------------------------------------------------
__global__ __launch_bounds__(64) void emis_kernel(const float* __restrict__ feats,
                                                  const float* __restrict__ Wout,
                                                  const float* __restrict__ bout,
                                                  const int* __restrict__ lens,
                                                  float* __restrict__ emis) {
    int r = blockIdx.x;
    int b = r >> 9, t = r & 511;
    if (t >= lens[b]) return;
    int lane = threadIdx.x;
    const float* fr = feats + (size_t)r * 512;
    float f[8];
#pragma unroll
    for (int i = 0; i < 8; ++i) f[i] = fr[i * 64 + lane];
#pragma unroll
    for (int k = 0; k < 9; ++k) {
        float p = 0.0f;
#pragma unroll
        for (int i = 0; i < 8; ++i) p = fmaf(f[i], Wout[k * 512 + i * 64 + lane], p);
#pragma unroll
        for (int off = 32; off; off >>= 1) p += __shfl_down(p, off);
        if (lane == 0) emis[r * 9 + k] = p + bout[k];
    }
}

// ---------------------------------------------------------------------------
// crf_kernel: alpha recursion + viterbi + backtrace + numerator + loss.
// ---------------------------------------------------------------------------
__global__ __launch_bounds__(64) void crf_kernel(const float* __restrict__ emis,
                                                 const int* __restrict__ lens,
                                                 const int* __restrict__ labels,
                                                 const float* __restrict__ start_trans,
                                                 const float* __restrict__ end_trans,
                                                 const float* __restrict__ trans,
                                                 float* __restrict__ out) {
    int b = blockIdx.x;
    int len = lens[b];
    int lane = threadIdx.x;
    __shared__ float alpha[9], vit[9];
    __shared__ unsigned char hist[512 * 9];
    const float* eb = emis + b * 512 * 9;
    const int* lb = labels + b * 512;

    float tr[9];
    if (lane < 9) {
#pragma unroll
        for (int i = 0; i < 9; ++i) tr[i] = trans[i * 9 + lane];
        float s0 = start_trans[lane] + eb[lane];
        alpha[lane] = s0;
        vit[lane] = s0;
    }
    __syncthreads();

    for (int t = 1; t < len; ++t) {
        float na = 0.0f, nv = 0.0f;
        if (lane < 9) {
            float e = eb[t * 9 + lane];
            float a[9];
#pragma unroll
            for (int i = 0; i < 9; ++i) a[i] = alpha[i] + tr[i];
            float m = a[0];
#pragma unroll
            for (int i = 1; i < 9; ++i) m = fmaxf(m, a[i]);
            float s = 0.0f;
#pragma unroll
            for (int i = 0; i < 9; ++i) s += __expf(a[i] - m);
            na = m + __logf(s) + e;
            float bv = vit[0] + tr[0];
            int bi = 0;
#pragma unroll
            for (int i = 1; i < 9; ++i) {
                float x = vit[i] + tr[i];
                if (x > bv) { bv = x; bi = i; }
            }
            nv = bv + e;
            hist[t * 9 + lane] = (unsigned char)bi;
        }
        __syncthreads();
        if (lane < 9) { alpha[lane] = na; vit[lane] = nv; }
        __syncthreads();
    }

    float part = 0.0f;
    for (int t = 1 + lane; t < len; t += 64) {
        int yp = lb[t - 1], y = lb[t];
        part += trans[yp * 9 + y] + eb[t * 9 + y];
    }
#pragma unroll
    for (int off = 32; off; off >>= 1) part += __shfl_down(part, off);

    if (lane == 0) {
        int y0 = lb[0];
        float num = start_trans[y0] + eb[y0] + part + end_trans[lb[len - 1]];
        float m = alpha[0] + end_trans[0];
        for (int j = 1; j < 9; ++j) m = fmaxf(m, alpha[j] + end_trans[j]);
        float s = 0.0f;
        for (int j = 0; j < 9; ++j) s += __expf(alpha[j] + end_trans[j] - m);
        float denom = m + __logf(s);
        atomicAdd(out, (denom - num) * (1.0f / 64.0f));

        float bm = vit[0] + end_trans[0];
        int cur = 0;
        for (int j = 1; j < 9; ++j) {
            float x = vit[j] + end_trans[j];
            if (x > bm) { bm = x; cur = j; }
        }
        float* preds = out + 1 + b * 512;
        preds[len - 1] = (float)cur;
        for (int t = len - 1; t >= 1; --t) {
            cur = hist[t * 9 + cur];
            preds[t - 1] = (float)cur;
        }
    }
}

// ---------------------------------------------------------------------------
extern "C" void kernel_launch(void* const* d_in, const int* in_sizes, int n_in,
                              void* d_out, int out_size, void* d_ws, size_t ws_size,
                              hipStream_t stream) {
    const int* widx = (const int*)d_in[0];
    const int* lens = (const int*)d_in[1];
    const int* labels = (const int*)d_in[2];
    const float* wvec = (const float*)d_in[3];
    const float* WihF = (const float*)d_in[4];
    const float* WhhF = (const float*)d_in[5];
    const float* bF = (const float*)d_in[6];
    const float* WihB = (const float*)d_in[7];
    const float* WhhB = (const float*)d_in[8];
    const float* bB = (const float*)d_in[9];
    const float* Wout = (const float*)d_in[10];
    const float* bout = (const float*)d_in[11];
    const float* start_trans = (const float*)d_in[12];
    const float* end_trans = (const float*)d_in[13];
    const float* trans9 = (const float*)d_in[14];
    float* out = (float*)d_out;
    char* ws = (char*)d_ws;

    // workspace layout (bytes)
    _Float16* gxF = (_Float16*)(ws);                        // 67,108,864
    _Float16* gxB = (_Float16*)(ws + 67108864);             // 67,108,864
    uint* wregF   = (uint*)(ws + 134217728);                // 106,496
    uint* wregB   = (uint*)(ws + 134324224);                // 106,496
    uint* wldsF   = (uint*)(ws + 134430720);                // 155,648
    uint* wldsB   = (uint*)(ws + 134586368);                // 155,648
    uint* wstrF   = (uint*)(ws + 134742016);                // 131,072
    uint* wstrB   = (uint*)(ws + 134873088);                // 131,072
    // wih16F/B live only before lstm; emis written after lstm -> safe alias
    uint* wih16F  = (uint*)(ws + 135004160);                // 524,288
    uint* wih16B  = (uint*)(ws + 135528448);                // 524,288
    float* emis   = (float*)(ws + 135004160);               // 1,179,648 (alias)
    (void)in_sizes; (void)n_in; (void)out_size; (void)ws_size;

    float* feats = out + 1 + 32768;   // feats output region (B,T,512) fp32

    zero_kernel<<<65665, 256, 0, stream>>>(out, lens);
    pack_kernel<<<1024, 256, 0, stream>>>(WhhF, WhhB, wregF, wregB, wldsF, wldsB,
                                          wstrF, wstrB);
    wih_pack_kernel<<<1024, 256, 0, stream>>>(WihF, WihB, wih16F, wih16B);

    dim3 ggrid(512, 16);
    gemm_gx_kernel<<<ggrid, 256, 0, stream>>>(widx, lens, wvec, wih16F, bF, gxF);
    gemm_gx_kernel<<<ggrid, 256, 0, stream>>>(widx, lens, wvec, wih16B, bB, gxB);

    lstm_kernel<<<128, 512, 0, stream>>>(gxF, gxB, wregF, wregB, wldsF, wldsB,
                                         wstrF, wstrB, lens, feats);

    emis_kernel<<<32768, 64, 0, stream>>>(feats, Wout, bout, lens, emis);
    crf_kernel<<<64, 64, 0, stream>>>(emis, lens, labels, start_trans, end_trans, trans9, out);
}